// Round 11
// baseline (3234.311 us; speedup 1.0000x reference)
//
#include <hip/hip_runtime.h>

// CausalTransformerBlock: B=4, S=4096, H=1024, NH=1, D_FF=4096, ktop=409.
// r10 post-mortem: T1 remap + causal skip = 1.85x per-XCD imbalance ->
// REVERTED. All pipes <25% busy => latency-bound on stage->vmcnt0->barrier.
// r11: 2-phase double-buffered K-loop (catalog T3-minimum): prefetch next
// K-tile BEFORE computing current; ONE barrier per step. Values identical.
// Also: trunc-split in AMODE2 staging (pair-sum still 2^-17 exact).
// ws: 8*32MiB + 4MiB + 384KiB = 273,022,976 B (proven r7-r10).

typedef unsigned short ushortT;
typedef short bf16x8 __attribute__((ext_vector_type(8)));
typedef float f32x4 __attribute__((ext_vector_type(4)));
typedef unsigned short us8 __attribute__((ext_vector_type(8)));

#define SEQ 4096
#define HDIM 1024
#define TOK 16384
#define DFF 4096
#define KTOP 409

__device__ __forceinline__ float b2f(unsigned short u) {
    return __uint_as_float(((unsigned)u) << 16);
}
__device__ __forceinline__ unsigned short f2b(float f) {
    unsigned u = __float_as_uint(f);
    u += 0x7fffu + ((u >> 16) & 1u);   // RNE
    return (unsigned short)(u >> 16);
}

__device__ __forceinline__ float blkRedF(float v, float* red4) {
    #pragma unroll
    for (int o = 32; o; o >>= 1) v += __shfl_xor(v, o);
    if ((threadIdx.x & 63) == 0) red4[threadIdx.x >> 6] = v;
    __syncthreads();
    v = red4[0] + red4[1] + red4[2] + red4[3];
    __syncthreads();
    return v;
}
__device__ __forceinline__ int blkRedI(int v, int* red4) {
    #pragma unroll
    for (int o = 32; o; o >>= 1) v += __shfl_xor(v, o);
    if ((threadIdx.x & 63) == 0) red4[threadIdx.x >> 6] = v;
    __syncthreads();
    v = red4[0] + red4[1] + red4[2] + red4[3];
    __syncthreads();
    return v;
}

// -------- f32 -> bf16 hi (+ optional lo residual) convert -------------------
template<int HASLO>
__global__ __launch_bounds__(256) void cvt2_k(const float* __restrict__ s,
                                              ushortT* __restrict__ hi,
                                              ushortT* __restrict__ lo) {
    const int i = (blockIdx.x * 256 + threadIdx.x) * 4;
    float4 v = *(const float4*)(s + i);
    float vv[4] = {v.x, v.y, v.z, v.w};
    ushort4 h, l;
    unsigned short* hp = &h.x; unsigned short* lp = &l.x;
    #pragma unroll
    for (int j = 0; j < 4; ++j) {
        hp[j] = f2b(vv[j]);
        if constexpr (HASLO) lp[j] = f2b(vv[j] - b2f(hp[j]));
    }
    *(ushort4*)(hi + i) = h;
    if constexpr (HASLO) *(ushort4*)(lo + i) = l;
}

// ---------------- LayerNorm: f32 in -> bf16 hi+lo out ------------------------
__global__ __launch_bounds__(256) void ln_k(const float* __restrict__ in,
                                            ushortT* __restrict__ ohi,
                                            ushortT* __restrict__ olo,
                                            const float* __restrict__ g,
                                            const float* __restrict__ b) {
    __shared__ float red4[4];
    const long long row = blockIdx.x;
    const int t = threadIdx.x;
    float4 v = ((const float4*)(in + row * HDIM))[t];
    float x[4] = {v.x, v.y, v.z, v.w};
    float s = x[0] + x[1] + x[2] + x[3];
    s = blkRedF(s, red4);
    const float mean = s * (1.0f / HDIM);
    float vs = 0.f;
    #pragma unroll
    for (int k2 = 0; k2 < 4; ++k2) { float d = x[k2] - mean; vs += d * d; }
    vs = blkRedF(vs, red4);
    const float inv = 1.0f / sqrtf(vs * (1.0f / HDIM) + 1e-5f);
    float4 gv = ((const float4*)g)[t];
    float4 bv = ((const float4*)b)[t];
    float o[4];
    o[0] = (x[0] - mean) * inv * gv.x + bv.x;
    o[1] = (x[1] - mean) * inv * gv.y + bv.y;
    o[2] = (x[2] - mean) * inv * gv.z + bv.z;
    o[3] = (x[3] - mean) * inv * gv.w + bv.w;
    ushort4 h, l;
    unsigned short* hp = &h.x; unsigned short* lp = &l.x;
    #pragma unroll
    for (int j = 0; j < 4; ++j) {
        hp[j] = f2b(o[j]);
        lp[j] = f2b(o[j] - b2f(hp[j]));
    }
    ((ushort4*)(ohi + row * HDIM))[t] = h;
    ((ushort4*)(olo + row * HDIM))[t] = l;
}

// ------------- rank-3 causal-bias precompute (h1 = hi+lo bf16) --------------
__global__ __launch_bounds__(256) void bias_pre(const ushortT* __restrict__ hhi,
        const ushortT* __restrict__ hlo,
        const float* __restrict__ cw, const float* __restrict__ cb,
        const float* __restrict__ ew, const float* __restrict__ eb,
        const float* __restrict__ st,
        float* __restrict__ e0, float* __restrict__ e1,
        float* __restrict__ uu, float* __restrict__ ww, float* __restrict__ zz) {
    const int tok = blockIdx.x * 4 + (threadIdx.x >> 6);
    const int L = threadIdx.x & 63;
    const long long base = (long long)tok * HDIM + L * 16;
    us8 h0 = *(const us8*)(hhi + base);
    us8 h1v = *(const us8*)(hhi + base + 8);
    us8 l0 = *(const us8*)(hlo + base);
    us8 l1v = *(const us8*)(hlo + base + 8);
    float hv[16];
    #pragma unroll
    for (int q = 0; q < 8; ++q) {
        hv[q] = b2f(h0[q]) + b2f(l0[q]);
        hv[8 + q] = b2f(h1v[q]) + b2f(l1v[q]);
    }
    float d0 = 0, d1 = 0, du = 0, dw = 0, dz = 0;
    #pragma unroll
    for (int q = 0; q < 16; ++q) {
        d0 += hv[q] * cw[L * 16 + q];
        d1 += hv[q] * cw[HDIM + L * 16 + q];
        du += hv[q] * ew[L * 16 + q];
        dw += hv[q] * ew[HDIM + L * 16 + q];
        dz += hv[q] * (eb[L * 16 + q] + eb[HDIM + L * 16 + q]);
    }
    #pragma unroll
    for (int o = 32; o; o >>= 1) {
        d0 += __shfl_xor(d0, o); d1 += __shfl_xor(d1, o);
        du += __shfl_xor(du, o); dw += __shfl_xor(dw, o); dz += __shfl_xor(dz, o);
    }
    if (L == 0) {
        e0[tok] = (d0 + cb[0]) * st[0];
        e1[tok] = (d1 + cb[1]) * st[1];
        uu[tok] = du; ww[tok] = dw; zz[tok] = dz;
    }
}

// ------------- triangular row-sum of exp-scores (cols <= s only) ------------
__global__ __launch_bounds__(256) void row_sum(const float* __restrict__ e,
                                               float* __restrict__ l) {
    __shared__ float red4[4];
    const int r = blockIdx.x;
    const int s = r & 4095;
    const float* rowp = e + (long long)r * SEQ;
    const int c0 = threadIdx.x * 16;
    float sum = 0.f;
    if (c0 + 15 <= s) {
        const float4* p = (const float4*)(rowp + c0);
        #pragma unroll
        for (int i = 0; i < 4; ++i) {
            float4 v = p[i];
            sum += v.x + v.y + v.z + v.w;
        }
    } else if (c0 <= s) {
        #pragma unroll
        for (int i = 0; i < 4; ++i) {
            float q0 = (c0 + i * 4 + 0 <= s) ? rowp[c0 + i * 4 + 0] : 0.f;
            float q1 = (c0 + i * 4 + 1 <= s) ? rowp[c0 + i * 4 + 1] : 0.f;
            float q2 = (c0 + i * 4 + 2 <= s) ? rowp[c0 + i * 4 + 2] : 0.f;
            float q3 = (c0 + i * 4 + 3 <= s) ? rowp[c0 + i * 4 + 3] : 0.f;
            sum += q0 + q1 + q2 + q3;
        }
    }
    sum = blkRedF(sum, red4);
    if (threadIdx.x == 0) l[r] = sum;
}

// --------- normalize attn in place; emits upper-triangle zeros --------------
__global__ __launch_bounds__(256) void attn_norm(float* __restrict__ attn,
                                                 const float* __restrict__ l) {
    const long long g = (long long)blockIdx.x * 256 + threadIdx.x;
    const long long base = g * 8;
    const int r = (int)(base >> 12);
    const int s = r & 4095;
    const int c = (int)(base & 4095);
    float4 z = {0.f, 0.f, 0.f, 0.f};
    if (c > s) {                       // never written by scores: store zeros
        *(float4*)(attn + base) = z;
        *(float4*)(attn + base + 4) = z;
        return;
    }
    const float inv = 1.0f / l[r];
    float4 v0 = *(const float4*)(attn + base);
    float4 v1 = *(const float4*)(attn + base + 4);
    if (c + 7 <= s) {
        v0.x *= inv; v0.y *= inv; v0.z *= inv; v0.w *= inv;
        v1.x *= inv; v1.y *= inv; v1.z *= inv; v1.w *= inv;
    } else {
        float vv[8] = {v0.x, v0.y, v0.z, v0.w, v1.x, v1.y, v1.z, v1.w};
        #pragma unroll
        for (int j = 0; j < 8; ++j) vv[j] = (c + j <= s) ? vv[j] * inv : 0.f;
        v0.x = vv[0]; v0.y = vv[1]; v0.z = vv[2]; v0.w = vv[3];
        v1.x = vv[4]; v1.y = vv[5]; v1.z = vv[6]; v1.w = vv[7];
    }
    *(float4*)(attn + base) = v0;
    *(float4*)(attn + base + 4) = v1;
}

// ------- exact top-409 select + mask-apply (binary search on key bits) ------
__global__ __launch_bounds__(256) void topk_mask(const float* __restrict__ logits,
                                                 ushortT* __restrict__ ff) {
    __shared__ int red4[4];
    __shared__ int sc[256];
    const long long row = blockIdx.x;
    const int t = threadIdx.x;
    const float* lg = logits + row * (long long)DFF + t * 16;
    unsigned key[16];
    #pragma unroll
    for (int q4 = 0; q4 < 4; ++q4) {
        float4 v = ((const float4*)lg)[q4];
        float vv[4] = {v.x, v.y, v.z, v.w};
        #pragma unroll
        for (int j = 0; j < 4; ++j) {
            unsigned u = __float_as_uint(vv[j]);
            key[q4 * 4 + j] = (u & 0x80000000u) ? ~u : (u | 0x80000000u);
        }
    }
    unsigned T = 0;
    for (int bit = 31; bit >= 0; --bit) {
        unsigned cand = T | (1u << bit);
        int c = 0;
        #pragma unroll
        for (int q = 0; q < 16; ++q) c += (key[q] >= cand);
        c = blkRedI(c, red4);
        if (c >= KTOP) T = cand;
    }
    int cg = 0, eq = 0;
    #pragma unroll
    for (int q = 0; q < 16; ++q) { cg += (key[q] > T); eq += (key[q] == T); }
    cg = blkRedI(cg, red4);
    const int need = KTOP - cg;
    sc[t] = eq;
    __syncthreads();
    for (int o = 1; o < 256; o <<= 1) {
        int x = (t >= o) ? sc[t - o] : 0;
        __syncthreads();
        sc[t] += x;
        __syncthreads();
    }
    int pre = sc[t] - eq;   // exclusive prefix of equal-count, index order
    ushortT* fr = ff + row * (long long)DFF + t * 16;
    #pragma unroll
    for (int q = 0; q < 16; ++q) {
        bool sel = (key[q] > T) || ((key[q] == T) && (pre < need));
        if (key[q] == T) pre++;
        if (!sel) fr[q] = 0;
    }
}

// ---------------- unified NT GEMM: C[M,N] = A[M,K] * B[N,K]^T ----------------
// 128x128 tile, 4 waves, BK=32, double-buffered LDS with prefetch-ahead
// (one barrier per K-step), XOR chunk-swizzle s(row)=(row>>1)&3.
//  AMODE: 0=A bf16 hi gload_lds; 2=A f32 -> hi+lo VALU-staged; 3=A hi+lo gload_lds
//  BMODE: 0=B bf16 hi gload_lds; 1=B hi+lo gload_lds
struct GemmP {
    const ushortT* A; const ushortT* A2; const float* Af;
    const ushortT* B; const ushortT* B2;
    long long aBatch, bBatch, oBatch;
    int lda, ldb, K, ldo;
    void* out; void* out2;
    const float* biasN; const float* biasN2; const float* biasM;
    const float *pe0, *pe1, *pu, *pw, *pz, *pl;
    const float* resF32;
    float scale;
    int nSplit;
};

// EPI: 2=f32 exp-scores(causal, skip-upper)  3=hi+lo PV*(1/l)  4=f32+biasN+res
//      5=gelu(.+biasN) bf16  6=hi+lo +biasN/biasN2  8=hi+lo +biasM  9=f32+biasN
template<int EPI, int AMODE, int BMODE>
__global__ __launch_bounds__(256) void gemm_nt(GemmP p) {
    __shared__ ushortT Ahi[2][4096];
    __shared__ ushortT Bhi[2][4096];
    __shared__ ushortT Alo[(AMODE >= 2) ? 2 : 1][(AMODE >= 2) ? 4096 : 8];
    __shared__ ushortT Blo[(BMODE == 1) ? 2 : 1][(BMODE == 1) ? 4096 : 8];
    const int tid = threadIdx.x;
    const int L = tid & 63;
    const int w = tid >> 6;
    const int wm = w >> 1, wn = w & 1;
    const int bn = blockIdx.x, bm = blockIdx.y, bz = blockIdx.z;

    f32x4 acc[4][4] = {};

    const long long obase = (long long)bz * p.oBatch;
    float* Of = (float*)p.out;
    ushortT* Oh = (ushortT*)p.out;
    ushortT* Ol = (ushortT*)p.out2;

    int gnv[4];
    #pragma unroll
    for (int j = 0; j < 4; ++j) gnv[j] = bn * 128 + wn * 64 + j * 16 + (L & 15);

    if constexpr (EPI == 2) {
        if (bn > bm) return;    // upper triangle: nothing to compute or write
    }

    int kEnd = p.K;
    if constexpr (EPI == 3) { kEnd = min(p.K, (bm + 1) * 128); }
    const int nt = kEnd >> 5;

    // gload_lds dest is linear (lane*16B); pre-swizzle the SOURCE chunk so
    // LDS[row][c] = global[row][c ^ s(row)], s(row)=(row>>1)&3; reads XOR same.
    const int r0row = tid >> 2;
    const int r1row = 64 + r0row;
    const int rc   = ((tid & 3) ^ ((tid >> 3) & 3)) * 8;    // source chunk
    const int qsw  = (((L >> 4) ^ ((L >> 1) & 3))) * 8;     // read chunk

    auto STAGE = [&](int sb, int k0) {
        if constexpr (AMODE != 2) {
            const ushortT* Ab = p.A + (long long)bz * p.aBatch
                              + (long long)bm * 128 * p.lda + k0 + rc;
            __builtin_amdgcn_global_load_lds(
                (const __attribute__((address_space(1))) void*)(Ab + (long long)r0row * p.lda),
                (__attribute__((address_space(3))) void*)(&Ahi[sb][w * 512]), 16, 0, 0);
            __builtin_amdgcn_global_load_lds(
                (const __attribute__((address_space(1))) void*)(Ab + (long long)r1row * p.lda),
                (__attribute__((address_space(3))) void*)(&Ahi[sb][2048 + w * 512]), 16, 0, 0);
            if constexpr (AMODE == 3) {
                const ushortT* Ab2 = p.A2 + (long long)bz * p.aBatch
                                   + (long long)bm * 128 * p.lda + k0 + rc;
                __builtin_amdgcn_global_load_lds(
                    (const __attribute__((address_space(1))) void*)(Ab2 + (long long)r0row * p.lda),
                    (__attribute__((address_space(3))) void*)(&Alo[sb][w * 512]), 16, 0, 0);
                __builtin_amdgcn_global_load_lds(
                    (const __attribute__((address_space(1))) void*)(Ab2 + (long long)r1row * p.lda),
                    (__attribute__((address_space(3))) void*)(&Alo[sb][2048 + w * 512]), 16, 0, 0);
            }
        } else {
            const int arow = tid >> 1;
            const float* ap = p.Af + (long long)bz * p.aBatch
                            + ((long long)bm * 128 + arow) * p.lda
                            + k0 + (tid & 1) * 16;
            #pragma unroll
            for (int cc = 0; cc < 2; ++cc) {
                const int c = (tid & 1) * 2 + cc;
                const int cs = (c ^ ((arow >> 1) & 3)) * 8;   // swizzled dest chunk
                float4 v0 = ((const float4*)ap)[cc * 2];
                float4 v1 = ((const float4*)ap)[cc * 2 + 1];
                float vv[8] = {v0.x, v0.y, v0.z, v0.w, v1.x, v1.y, v1.z, v1.w};
                us8 h, l;
                #pragma unroll
                for (int j = 0; j < 8; ++j) {
                    h[j] = (ushortT)(__float_as_uint(vv[j]) >> 16);   // trunc hi
                    l[j] = f2b(vv[j] - b2f(h[j]));                    // exact-ish lo
                }
                *(us8*)(&Ahi[sb][arow * 32 + cs]) = h;
                *(us8*)(&Alo[sb][arow * 32 + cs]) = l;
            }
        }
        {
            const ushortT* Bb = p.B + (long long)bz * p.bBatch
                              + (long long)bn * 128 * p.ldb + k0 + rc;
            __builtin_amdgcn_global_load_lds(
                (const __attribute__((address_space(1))) void*)(Bb + (long long)r0row * p.ldb),
                (__attribute__((address_space(3))) void*)(&Bhi[sb][w * 512]), 16, 0, 0);
            __builtin_amdgcn_global_load_lds(
                (const __attribute__((address_space(1))) void*)(Bb + (long long)r1row * p.ldb),
                (__attribute__((address_space(3))) void*)(&Bhi[sb][2048 + w * 512]), 16, 0, 0);
            if constexpr (BMODE == 1) {
                const ushortT* Bb2 = p.B2 + (long long)bz * p.bBatch
                                   + (long long)bn * 128 * p.ldb + k0 + rc;
                __builtin_amdgcn_global_load_lds(
                    (const __attribute__((address_space(1))) void*)(Bb2 + (long long)r0row * p.ldb),
                    (__attribute__((address_space(3))) void*)(&Blo[sb][w * 512]), 16, 0, 0);
                __builtin_amdgcn_global_load_lds(
                    (const __attribute__((address_space(1))) void*)(Bb2 + (long long)r1row * p.ldb),
                    (__attribute__((address_space(3))) void*)(&Blo[sb][2048 + w * 512]), 16, 0, 0);
            }
        }
    };

    // prologue: stage tile 0, drain, then loop with prefetch-ahead.
    STAGE(0, 0);
    __syncthreads();
    int cur = 0;
    for (int t = 0; ; ) {
        if (t + 1 < nt) STAGE(cur ^ 1, (t + 1) << 5);   // prefetch next tile
        {
            bf16x8 ah[4], bh[4];
            #pragma unroll
            for (int i = 0; i < 4; ++i)
                ah[i] = *(const bf16x8*)(&Ahi[cur][(wm * 64 + i * 16 + (L & 15)) * 32 + qsw]);
            #pragma unroll
            for (int j = 0; j < 4; ++j)
                bh[j] = *(const bf16x8*)(&Bhi[cur][(wn * 64 + j * 16 + (L & 15)) * 32 + qsw]);
            #pragma unroll
            for (int i = 0; i < 4; ++i)
                #pragma unroll
                for (int j = 0; j < 4; ++j)
                    acc[i][j] = __builtin_amdgcn_mfma_f32_16x16x32_bf16(ah[i], bh[j], acc[i][j], 0, 0, 0);
            if constexpr (BMODE == 1) {
                bf16x8 bl[4];
                #pragma unroll
                for (int j = 0; j < 4; ++j)
                    bl[j] = *(const bf16x8*)(&Blo[cur][(wn * 64 + j * 16 + (L & 15)) * 32 + qsw]);
                #pragma unroll
                for (int i = 0; i < 4; ++i)
                    #pragma unroll
                    for (int j = 0; j < 4; ++j)
                        acc[i][j] = __builtin_amdgcn_mfma_f32_16x16x32_bf16(ah[i], bl[j], acc[i][j], 0, 0, 0);
            }
            if constexpr (AMODE >= 2) {
                bf16x8 al[4];
                #pragma unroll
                for (int i = 0; i < 4; ++i)
                    al[i] = *(const bf16x8*)(&Alo[cur][(wm * 64 + i * 16 + (L & 15)) * 32 + qsw]);
                #pragma unroll
                for (int i = 0; i < 4; ++i)
                    #pragma unroll
                    for (int j = 0; j < 4; ++j)
                        acc[i][j] = __builtin_amdgcn_mfma_f32_16x16x32_bf16(al[i], bh[j], acc[i][j], 0, 0, 0);
            }
        }
        ++t;
        if (t >= nt) break;
        __syncthreads();     // drains prefetch (vmcnt0) + guards buffer swap
        cur ^= 1;
    }

    float c0[4], c1[4], c2[4];
    #pragma unroll
    for (int j = 0; j < 4; ++j) {
        if constexpr (EPI == 2) {
            c0[j] = p.pu[bz * SEQ + gnv[j]];
            c1[j] = p.pw[bz * SEQ + gnv[j]];
            c2[j] = p.pz[bz * SEQ + gnv[j]];
        } else if constexpr (EPI == 6) {
            c0[j] = (gnv[j] < p.nSplit) ? p.biasN[gnv[j]]
                                        : p.biasN2[gnv[j] - p.nSplit];
        } else if constexpr (EPI == 4 || EPI == 5 || EPI == 9) {
            c0[j] = p.biasN[gnv[j]];
        }
    }

    #pragma unroll
    for (int i = 0; i < 4; ++i) {
        #pragma unroll
        for (int r = 0; r < 4; ++r) {
            const int gm = bm * 128 + wm * 64 + i * 16 + ((L >> 4) << 2) + r;
            float rA = 0.f, rB = 0.f, mult = 1.f;
            if constexpr (EPI == 2) { rA = p.pe0[bz * SEQ + gm]; rB = p.pe1[bz * SEQ + gm]; }
            if constexpr (EPI == 3) mult = 1.0f / p.pl[bz * SEQ + gm];
            if constexpr (EPI == 8) rA = p.biasM[gm];
            #pragma unroll
            for (int j = 0; j < 4; ++j) {
                float v = acc[i][j][r];
                const long long oidx = obase + (long long)gm * p.ldo + gnv[j];
                if constexpr (EPI == 2) {
                    float s = v * p.scale + rA * c0[j] + rB * c1[j] + c2[j];
                    Of[oidx] = (gnv[j] <= gm) ? __expf(s) : 0.f;
                } else if constexpr (EPI == 3) {
                    float val = v * mult;
                    ushortT h = f2b(val);
                    Oh[oidx] = h; Ol[oidx] = f2b(val - b2f(h));
                } else if constexpr (EPI == 4) {
                    Of[oidx] = v + c0[j] + p.resF32[(long long)gm * p.ldo + gnv[j]];
                } else if constexpr (EPI == 5) {
                    float tt = v + c0[j];
                    Oh[oidx] = f2b(0.5f * tt * (1.0f + erff(tt * 0.70710678118654752f)));
                } else if constexpr (EPI == 6) {
                    float val = v + c0[j];
                    ushortT h = f2b(val);
                    Oh[oidx] = h; Ol[oidx] = f2b(val - b2f(h));
                } else if constexpr (EPI == 8) {
                    float val = v + rA;
                    ushortT h = f2b(val);
                    Oh[oidx] = h; Ol[oidx] = f2b(val - b2f(h));
                } else if constexpr (EPI == 9) {
                    Of[oidx] = v + c0[j];
                }
            }
        }
    }
}

// ------------------------------- host driver --------------------------------
extern "C" void kernel_launch(void* const* d_in, const int* in_sizes, int n_in,
                              void* d_out, int out_size, void* d_ws, size_t ws_size,
                              hipStream_t stream) {
    (void)in_sizes; (void)n_in; (void)out_size; (void)ws_size;
    const float* x    = (const float*)d_in[0];
    const float* wq   = (const float*)d_in[2];
    const float* bq   = (const float*)d_in[3];
    const float* wk   = (const float*)d_in[4];
    const float* bk   = (const float*)d_in[5];
    const float* wv   = (const float*)d_in[6];
    const float* bv   = (const float*)d_in[7];
    const float* wo   = (const float*)d_in[8];
    const float* bo   = (const float*)d_in[9];
    const float* ln1g = (const float*)d_in[10];
    const float* ln1b = (const float*)d_in[11];
    const float* ln2g = (const float*)d_in[12];
    const float* ln2b = (const float*)d_in[13];
    const float* fc1w = (const float*)d_in[14];
    const float* fc1b = (const float*)d_in[15];
    const float* fc2w = (const float*)d_in[16];
    const float* fc2b = (const float*)d_in[17];
    const float* rww  = (const float*)d_in[18];
    const float* rwb  = (const float*)d_in[19];
    const float* cw   = (const float*)d_in[20];
    const float* cb   = (const float*)d_in[21];
    const float* ew   = (const float*)d_in[22];
    const float* eb   = (const float*)d_in[23];
    const float* st   = (const float*)d_in[24];

    char* ws = (char*)d_ws;
    const size_t MB32 = 33554432;
    // s0 h1hi, s1 h1lo | s2+s3 qkhi[16384][2048], s4+s5 qklo | s6 vthi, s7 vtlo
    // wqk bf16 JIT at s6 (8MB, dead before vt GEMM writes s6).
    // After scores: ctxhi->s2, ctxlo->s3 | x1 f32 -> s0+s1 | h2 -> s4,s5
    // FFN: fw -> s6 (32MB) | logc f32 -> s2+s3 (64MB) | ffc bf16 -> s7 (32MB)
    ushortT* h1hi = (ushortT*)(ws + 0 * MB32);
    ushortT* h1lo = (ushortT*)(ws + 1 * MB32);
    ushortT* qkhi = (ushortT*)(ws + 2 * MB32);
    ushortT* qklo = (ushortT*)(ws + 4 * MB32);
    ushortT* vthi = (ushortT*)(ws + 6 * MB32);
    ushortT* vtlo = (ushortT*)(ws + 7 * MB32);
    ushortT* wqkh = (ushortT*)(ws + 6 * MB32);           // 4MB (before vt)
    ushortT* wqkl = wqkh + 2 * (size_t)(HDIM * HDIM);    // 4MB
    ushortT* ctxhi = (ushortT*)(ws + 2 * MB32);
    ushortT* ctxlo = (ushortT*)(ws + 3 * MB32);
    float*   x1   = (float*)(ws + 0 * MB32);
    ushortT* h2hi = (ushortT*)(ws + 4 * MB32);
    ushortT* h2lo = (ushortT*)(ws + 5 * MB32);
    ushortT* fw   = vthi;
    float*   logc = (float*)(ws + 2 * MB32);
    ushortT* ffc  = (ushortT*)(ws + 7 * MB32);
    char* tail = ws + 8 * MB32;
    ushortT* whi = (ushortT*)(tail);                    // 2MB JIT weight hi
    ushortT* wlo = (ushortT*)(tail + 2097152);          // 2MB JIT weight lo
    char* sm = tail + 4194304;
    float* e0v = (float*)(sm);
    float* e1v = (float*)(sm + 1 * 65536);
    float* uu  = (float*)(sm + 2 * 65536);
    float* wwp = (float*)(sm + 3 * 65536);
    float* zz  = (float*)(sm + 4 * 65536);
    float* lrow = (float*)(sm + 5 * 65536);

    const int NW = HDIM * HDIM;
    const int NF = DFF * HDIM;
    ushortT* fc1h = fw;
    ushortT* fc2h = fw + 1 * (size_t)NF;
    ushortT* rwh  = fw + 2 * (size_t)NF;
    ushortT* rwl  = fw + 3 * (size_t)NF;

    float* outx = (float*)d_out;
    float* attn = outx + (size_t)TOK * HDIM;    // f32 [B,1,S,S]

    // --- attention sub-block ---
    ln_k<<<TOK, 256, 0, stream>>>(x, h1hi, h1lo, ln1g, ln1b);

    // qk = h1*[wq;wk]^T + [bq;bk] -> hi+lo  (N=2048 merged)
    cvt2_k<1><<<NW / 1024, 256, 0, stream>>>(wq, wqkh, wqkl);
    cvt2_k<1><<<NW / 1024, 256, 0, stream>>>(wk, wqkh + NW, wqkl + NW);
    GemmP pq{};
    pq.A = h1hi; pq.A2 = h1lo; pq.B = wqkh; pq.B2 = wqkl;
    pq.lda = HDIM; pq.ldb = HDIM; pq.K = HDIM; pq.ldo = 2048;
    pq.out = qkhi; pq.out2 = qklo;
    pq.biasN = bq; pq.biasN2 = bk; pq.nSplit = 1024;
    gemm_nt<6, 3, 1><<<dim3(16, 128, 1), 256, 0, stream>>>(pq);

    // vt[d,t] = wv[d,:]*h1[t,:] + bv[d]  -> hi+lo
    cvt2_k<1><<<NW / 1024, 256, 0, stream>>>(wv, whi, wlo);
    GemmP pv{};
    pv.A = whi; pv.A2 = wlo; pv.B = h1hi; pv.B2 = h1lo;
    pv.lda = HDIM; pv.ldb = HDIM; pv.K = HDIM; pv.ldo = SEQ;
    pv.aBatch = 0; pv.bBatch = (long long)SEQ * HDIM; pv.oBatch = (long long)HDIM * SEQ;
    pv.out = vthi; pv.out2 = vtlo; pv.biasM = bv;
    gemm_nt<8, 3, 1><<<dim3(32, 8, 4), 256, 0, stream>>>(pv);

    bias_pre<<<4096, 256, 0, stream>>>(h1hi, h1lo, cw, cb, ew, eb, st, e0v, e1v, uu, wwp, zz);

    // scores -> exp (q x k from merged buffer; lower triangle only)
    GemmP ps{};
    ps.A = qkhi; ps.A2 = qklo; ps.B = qkhi + 1024; ps.B2 = qklo + 1024;
    ps.lda = 2048; ps.ldb = 2048; ps.K = HDIM; ps.ldo = SEQ;
    ps.aBatch = (long long)SEQ * 2048; ps.bBatch = (long long)SEQ * 2048;
    ps.oBatch = (long long)SEQ * SEQ;
    ps.out = attn; ps.scale = 0.03125f;  // 1/sqrt(1024)
    ps.pe0 = e0v; ps.pe1 = e1v; ps.pu = uu; ps.pw = wwp; ps.pz = zz;
    gemm_nt<2, 3, 1><<<dim3(32, 32, 4), 256, 0, stream>>>(ps);

    row_sum<<<TOK, 256, 0, stream>>>(attn, lrow);

    // ctx = (e * vt^T) / l -> hi+lo   (e f32 staged, vt hi+lo gload_lds)
    GemmP pp{};
    pp.Af = attn; pp.B = vthi; pp.B2 = vtlo;
    pp.lda = SEQ; pp.ldb = SEQ; pp.K = SEQ; pp.ldo = HDIM;
    pp.aBatch = (long long)SEQ * SEQ; pp.bBatch = (long long)HDIM * SEQ;
    pp.oBatch = (long long)SEQ * HDIM;
    pp.out = ctxhi; pp.out2 = ctxlo; pp.pl = lrow;
    gemm_nt<3, 2, 1><<<dim3(8, 32, 4), 256, 0, stream>>>(pp);

    attn_norm<<<32768, 256, 0, stream>>>(attn, lrow);

    // x1 = x + ctx*wo^T + bo  (ctx hi+lo x wo hi+lo JIT)
    cvt2_k<1><<<NW / 1024, 256, 0, stream>>>(wo, whi, wlo);
    GemmP po{};
    po.A = ctxhi; po.A2 = ctxlo; po.B = whi; po.B2 = wlo;
    po.lda = HDIM; po.ldb = HDIM; po.K = HDIM; po.ldo = HDIM;
    po.out = x1; po.biasN = bo; po.resF32 = x;
    gemm_nt<4, 3, 1><<<dim3(8, 128, 1), 256, 0, stream>>>(po);

    // --- sparse FFN sub-block ---
    ln_k<<<TOK, 256, 0, stream>>>(x1, h2hi, h2lo, ln2g, ln2b);

    cvt2_k<0><<<NF / 1024, 256, 0, stream>>>(fc1w, fc1h, nullptr);
    cvt2_k<0><<<NF / 1024, 256, 0, stream>>>(fc2w, fc2h, nullptr);
    cvt2_k<1><<<NF / 1024, 256, 0, stream>>>(rww, rwh, rwl);

    for (int c = 0; c < 4; ++c) {
        const size_t roff = (size_t)c * 4096 * HDIM;
        GemmP pf{};
        pf.A = h2hi + roff; pf.B = fc1h;
        pf.lda = HDIM; pf.ldb = HDIM; pf.K = HDIM; pf.ldo = DFF;
        pf.out = ffc; pf.biasN = fc1b;
        gemm_nt<5, 0, 0><<<dim3(32, 32, 1), 256, 0, stream>>>(pf);

        GemmP pr{};
        pr.A = h2hi + roff; pr.A2 = h2lo + roff; pr.B = rwh; pr.B2 = rwl;
        pr.lda = HDIM; pr.ldb = HDIM; pr.K = HDIM; pr.ldo = DFF;
        pr.out = logc; pr.biasN = rwb;
        gemm_nt<9, 3, 1><<<dim3(32, 32, 1), 256, 0, stream>>>(pr);

        topk_mask<<<4096, 256, 0, stream>>>(logc, ffc);

        GemmP p2{};
        p2.A = ffc; p2.B = fc2h; p2.lda = DFF; p2.ldb = DFF; p2.K = DFF; p2.ldo = HDIM;
        p2.out = outx + roff; p2.biasN = fc2b;
        p2.resF32 = x1 + roff;
        gemm_nt<4, 0, 0><<<dim3(8, 32, 1), 256, 0, stream>>>(p2);
    }
}

// Round 12
// 2872.408 us; speedup vs baseline: 1.1260x; 1.1260x over previous
//
#include <hip/hip_runtime.h>

// CausalTransformerBlock: B=4, S=4096, H=1024, NH=1, D_FF=4096, ktop=409.
// r11 post-mortem: __syncthreads-per-step = vmcnt(0) drain -> dbuf placebo
// (m99/m139). r12: T4 counted vmcnt. STAGE(next) -> s_waitcnt vmcnt(NLOADS)
// (waits CURRENT tile, issued a full iter ago) -> raw s_barrier -> MFMA ->
// raw s_barrier. Next-tile loads stay in flight across BOTH barriers.
// Values bit-identical to r11 (canary: absmax == 0.09716797).
// ws: 8*32MiB + 4MiB + 384KiB = 273,022,976 B (proven r7-r11).

typedef unsigned short ushortT;
typedef short bf16x8 __attribute__((ext_vector_type(8)));
typedef float f32x4 __attribute__((ext_vector_type(4)));
typedef unsigned short us8 __attribute__((ext_vector_type(8)));

#define SEQ 4096
#define HDIM 1024
#define TOK 16384
#define DFF 4096
#define KTOP 409

__device__ __forceinline__ float b2f(unsigned short u) {
    return __uint_as_float(((unsigned)u) << 16);
}
__device__ __forceinline__ unsigned short f2b(float f) {
    unsigned u = __float_as_uint(f);
    u += 0x7fffu + ((u >> 16) & 1u);   // RNE
    return (unsigned short)(u >> 16);
}

__device__ __forceinline__ float blkRedF(float v, float* red4) {
    #pragma unroll
    for (int o = 32; o; o >>= 1) v += __shfl_xor(v, o);
    if ((threadIdx.x & 63) == 0) red4[threadIdx.x >> 6] = v;
    __syncthreads();
    v = red4[0] + red4[1] + red4[2] + red4[3];
    __syncthreads();
    return v;
}
__device__ __forceinline__ int blkRedI(int v, int* red4) {
    #pragma unroll
    for (int o = 32; o; o >>= 1) v += __shfl_xor(v, o);
    if ((threadIdx.x & 63) == 0) red4[threadIdx.x >> 6] = v;
    __syncthreads();
    v = red4[0] + red4[1] + red4[2] + red4[3];
    __syncthreads();
    return v;
}

// -------- f32 -> bf16 hi (+ optional lo residual) convert -------------------
template<int HASLO>
__global__ __launch_bounds__(256) void cvt2_k(const float* __restrict__ s,
                                              ushortT* __restrict__ hi,
                                              ushortT* __restrict__ lo) {
    const int i = (blockIdx.x * 256 + threadIdx.x) * 4;
    float4 v = *(const float4*)(s + i);
    float vv[4] = {v.x, v.y, v.z, v.w};
    ushort4 h, l;
    unsigned short* hp = &h.x; unsigned short* lp = &l.x;
    #pragma unroll
    for (int j = 0; j < 4; ++j) {
        hp[j] = f2b(vv[j]);
        if constexpr (HASLO) lp[j] = f2b(vv[j] - b2f(hp[j]));
    }
    *(ushort4*)(hi + i) = h;
    if constexpr (HASLO) *(ushort4*)(lo + i) = l;
}

// ---------------- LayerNorm: f32 in -> bf16 hi+lo out ------------------------
__global__ __launch_bounds__(256) void ln_k(const float* __restrict__ in,
                                            ushortT* __restrict__ ohi,
                                            ushortT* __restrict__ olo,
                                            const float* __restrict__ g,
                                            const float* __restrict__ b) {
    __shared__ float red4[4];
    const long long row = blockIdx.x;
    const int t = threadIdx.x;
    float4 v = ((const float4*)(in + row * HDIM))[t];
    float x[4] = {v.x, v.y, v.z, v.w};
    float s = x[0] + x[1] + x[2] + x[3];
    s = blkRedF(s, red4);
    const float mean = s * (1.0f / HDIM);
    float vs = 0.f;
    #pragma unroll
    for (int k2 = 0; k2 < 4; ++k2) { float d = x[k2] - mean; vs += d * d; }
    vs = blkRedF(vs, red4);
    const float inv = 1.0f / sqrtf(vs * (1.0f / HDIM) + 1e-5f);
    float4 gv = ((const float4*)g)[t];
    float4 bv = ((const float4*)b)[t];
    float o[4];
    o[0] = (x[0] - mean) * inv * gv.x + bv.x;
    o[1] = (x[1] - mean) * inv * gv.y + bv.y;
    o[2] = (x[2] - mean) * inv * gv.z + bv.z;
    o[3] = (x[3] - mean) * inv * gv.w + bv.w;
    ushort4 h, l;
    unsigned short* hp = &h.x; unsigned short* lp = &l.x;
    #pragma unroll
    for (int j = 0; j < 4; ++j) {
        hp[j] = f2b(o[j]);
        lp[j] = f2b(o[j] - b2f(hp[j]));
    }
    ((ushort4*)(ohi + row * HDIM))[t] = h;
    ((ushort4*)(olo + row * HDIM))[t] = l;
}

// ------------- rank-3 causal-bias precompute (h1 = hi+lo bf16) --------------
__global__ __launch_bounds__(256) void bias_pre(const ushortT* __restrict__ hhi,
        const ushortT* __restrict__ hlo,
        const float* __restrict__ cw, const float* __restrict__ cb,
        const float* __restrict__ ew, const float* __restrict__ eb,
        const float* __restrict__ st,
        float* __restrict__ e0, float* __restrict__ e1,
        float* __restrict__ uu, float* __restrict__ ww, float* __restrict__ zz) {
    const int tok = blockIdx.x * 4 + (threadIdx.x >> 6);
    const int L = threadIdx.x & 63;
    const long long base = (long long)tok * HDIM + L * 16;
    us8 h0 = *(const us8*)(hhi + base);
    us8 h1v = *(const us8*)(hhi + base + 8);
    us8 l0 = *(const us8*)(hlo + base);
    us8 l1v = *(const us8*)(hlo + base + 8);
    float hv[16];
    #pragma unroll
    for (int q = 0; q < 8; ++q) {
        hv[q] = b2f(h0[q]) + b2f(l0[q]);
        hv[8 + q] = b2f(h1v[q]) + b2f(l1v[q]);
    }
    float d0 = 0, d1 = 0, du = 0, dw = 0, dz = 0;
    #pragma unroll
    for (int q = 0; q < 16; ++q) {
        d0 += hv[q] * cw[L * 16 + q];
        d1 += hv[q] * cw[HDIM + L * 16 + q];
        du += hv[q] * ew[L * 16 + q];
        dw += hv[q] * ew[HDIM + L * 16 + q];
        dz += hv[q] * (eb[L * 16 + q] + eb[HDIM + L * 16 + q]);
    }
    #pragma unroll
    for (int o = 32; o; o >>= 1) {
        d0 += __shfl_xor(d0, o); d1 += __shfl_xor(d1, o);
        du += __shfl_xor(du, o); dw += __shfl_xor(dw, o); dz += __shfl_xor(dz, o);
    }
    if (L == 0) {
        e0[tok] = (d0 + cb[0]) * st[0];
        e1[tok] = (d1 + cb[1]) * st[1];
        uu[tok] = du; ww[tok] = dw; zz[tok] = dz;
    }
}

// ------------- triangular row-sum of exp-scores (cols <= s only) ------------
__global__ __launch_bounds__(256) void row_sum(const float* __restrict__ e,
                                               float* __restrict__ l) {
    __shared__ float red4[4];
    const int r = blockIdx.x;
    const int s = r & 4095;
    const float* rowp = e + (long long)r * SEQ;
    const int c0 = threadIdx.x * 16;
    float sum = 0.f;
    if (c0 + 15 <= s) {
        const float4* p = (const float4*)(rowp + c0);
        #pragma unroll
        for (int i = 0; i < 4; ++i) {
            float4 v = p[i];
            sum += v.x + v.y + v.z + v.w;
        }
    } else if (c0 <= s) {
        #pragma unroll
        for (int i = 0; i < 4; ++i) {
            float q0 = (c0 + i * 4 + 0 <= s) ? rowp[c0 + i * 4 + 0] : 0.f;
            float q1 = (c0 + i * 4 + 1 <= s) ? rowp[c0 + i * 4 + 1] : 0.f;
            float q2 = (c0 + i * 4 + 2 <= s) ? rowp[c0 + i * 4 + 2] : 0.f;
            float q3 = (c0 + i * 4 + 3 <= s) ? rowp[c0 + i * 4 + 3] : 0.f;
            sum += q0 + q1 + q2 + q3;
        }
    }
    sum = blkRedF(sum, red4);
    if (threadIdx.x == 0) l[r] = sum;
}

// --------- normalize attn in place; emits upper-triangle zeros --------------
__global__ __launch_bounds__(256) void attn_norm(float* __restrict__ attn,
                                                 const float* __restrict__ l) {
    const long long g = (long long)blockIdx.x * 256 + threadIdx.x;
    const long long base = g * 8;
    const int r = (int)(base >> 12);
    const int s = r & 4095;
    const int c = (int)(base & 4095);
    float4 z = {0.f, 0.f, 0.f, 0.f};
    if (c > s) {                       // never written by scores: store zeros
        *(float4*)(attn + base) = z;
        *(float4*)(attn + base + 4) = z;
        return;
    }
    const float inv = 1.0f / l[r];
    float4 v0 = *(const float4*)(attn + base);
    float4 v1 = *(const float4*)(attn + base + 4);
    if (c + 7 <= s) {
        v0.x *= inv; v0.y *= inv; v0.z *= inv; v0.w *= inv;
        v1.x *= inv; v1.y *= inv; v1.z *= inv; v1.w *= inv;
    } else {
        float vv[8] = {v0.x, v0.y, v0.z, v0.w, v1.x, v1.y, v1.z, v1.w};
        #pragma unroll
        for (int j = 0; j < 8; ++j) vv[j] = (c + j <= s) ? vv[j] * inv : 0.f;
        v0.x = vv[0]; v0.y = vv[1]; v0.z = vv[2]; v0.w = vv[3];
        v1.x = vv[4]; v1.y = vv[5]; v1.z = vv[6]; v1.w = vv[7];
    }
    *(float4*)(attn + base) = v0;
    *(float4*)(attn + base + 4) = v1;
}

// ------- exact top-409 select + mask-apply (binary search on key bits) ------
__global__ __launch_bounds__(256) void topk_mask(const float* __restrict__ logits,
                                                 ushortT* __restrict__ ff) {
    __shared__ int red4[4];
    __shared__ int sc[256];
    const long long row = blockIdx.x;
    const int t = threadIdx.x;
    const float* lg = logits + row * (long long)DFF + t * 16;
    unsigned key[16];
    #pragma unroll
    for (int q4 = 0; q4 < 4; ++q4) {
        float4 v = ((const float4*)lg)[q4];
        float vv[4] = {v.x, v.y, v.z, v.w};
        #pragma unroll
        for (int j = 0; j < 4; ++j) {
            unsigned u = __float_as_uint(vv[j]);
            key[q4 * 4 + j] = (u & 0x80000000u) ? ~u : (u | 0x80000000u);
        }
    }
    unsigned T = 0;
    for (int bit = 31; bit >= 0; --bit) {
        unsigned cand = T | (1u << bit);
        int c = 0;
        #pragma unroll
        for (int q = 0; q < 16; ++q) c += (key[q] >= cand);
        c = blkRedI(c, red4);
        if (c >= KTOP) T = cand;
    }
    int cg = 0, eq = 0;
    #pragma unroll
    for (int q = 0; q < 16; ++q) { cg += (key[q] > T); eq += (key[q] == T); }
    cg = blkRedI(cg, red4);
    const int need = KTOP - cg;
    sc[t] = eq;
    __syncthreads();
    for (int o = 1; o < 256; o <<= 1) {
        int x = (t >= o) ? sc[t - o] : 0;
        __syncthreads();
        sc[t] += x;
        __syncthreads();
    }
    int pre = sc[t] - eq;   // exclusive prefix of equal-count, index order
    ushortT* fr = ff + row * (long long)DFF + t * 16;
    #pragma unroll
    for (int q = 0; q < 16; ++q) {
        bool sel = (key[q] > T) || ((key[q] == T) && (pre < need));
        if (key[q] == T) pre++;
        if (!sel) fr[q] = 0;
    }
}

// ---------------- unified NT GEMM: C[M,N] = A[M,K] * B[N,K]^T ----------------
// 128x128 tile, 4 waves, BK=32, double-buffered LDS, counted-vmcnt pipeline
// (T4): next-tile loads stay in flight across both barriers; vmcnt waits on
// the CURRENT tile's loads (issued one full iteration earlier -> ~0 stall).
// XOR chunk-swizzle s(row)=(row>>1)&3.
//  AMODE: 0=A bf16 hi gload_lds; 2=A f32 -> hi+lo VALU-staged; 3=A hi+lo gload_lds
//  BMODE: 0=B bf16 hi gload_lds; 1=B hi+lo gload_lds
struct GemmP {
    const ushortT* A; const ushortT* A2; const float* Af;
    const ushortT* B; const ushortT* B2;
    long long aBatch, bBatch, oBatch;
    int lda, ldb, K, ldo;
    void* out; void* out2;
    const float* biasN; const float* biasN2; const float* biasM;
    const float *pe0, *pe1, *pu, *pw, *pz, *pl;
    const float* resF32;
    float scale;
    int nSplit;
};

// EPI: 2=f32 exp-scores(causal, skip-upper)  3=hi+lo PV*(1/l)  4=f32+biasN+res
//      5=gelu(.+biasN) bf16  6=hi+lo +biasN/biasN2  8=hi+lo +biasM  9=f32+biasN
template<int EPI, int AMODE, int BMODE>
__global__ __launch_bounds__(256) void gemm_nt(GemmP p) {
    __shared__ ushortT Ahi[2][4096];
    __shared__ ushortT Bhi[2][4096];
    __shared__ ushortT Alo[(AMODE >= 2) ? 2 : 1][(AMODE >= 2) ? 4096 : 8];
    __shared__ ushortT Blo[(BMODE == 1) ? 2 : 1][(BMODE == 1) ? 4096 : 8];
    const int tid = threadIdx.x;
    const int L = tid & 63;
    const int w = tid >> 6;
    const int wm = w >> 1, wn = w & 1;
    const int bn = blockIdx.x, bm = blockIdx.y, bz = blockIdx.z;

    f32x4 acc[4][4] = {};

    const long long obase = (long long)bz * p.oBatch;
    float* Of = (float*)p.out;
    ushortT* Oh = (ushortT*)p.out;
    ushortT* Ol = (ushortT*)p.out2;

    int gnv[4];
    #pragma unroll
    for (int j = 0; j < 4; ++j) gnv[j] = bn * 128 + wn * 64 + j * 16 + (L & 15);

    if constexpr (EPI == 2) {
        if (bn > bm) return;    // upper triangle: nothing to compute or write
    }

    int kEnd = p.K;
    if constexpr (EPI == 3) { kEnd = min(p.K, (bm + 1) * 128); }
    const int nt = kEnd >> 5;

    // gload_lds dest is linear (lane*16B); pre-swizzle the SOURCE chunk so
    // LDS[row][c] = global[row][c ^ s(row)], s(row)=(row>>1)&3; reads XOR same.
    const int r0row = tid >> 2;
    const int r1row = 64 + r0row;
    const int rc   = ((tid & 3) ^ ((tid >> 3) & 3)) * 8;    // source chunk
    const int qsw  = (((L >> 4) ^ ((L >> 1) & 3))) * 8;     // read chunk

    // gloads issued per thread per STAGE (vmcnt units)
    constexpr int NLOADS = ((AMODE == 3) ? 4 : (AMODE == 0) ? 2 : 0)
                         + ((BMODE == 1) ? 4 : 2);

    auto STAGE = [&](int sb, int k0) {
        if constexpr (AMODE != 2) {
            const ushortT* Ab = p.A + (long long)bz * p.aBatch
                              + (long long)bm * 128 * p.lda + k0 + rc;
            __builtin_amdgcn_global_load_lds(
                (const __attribute__((address_space(1))) void*)(Ab + (long long)r0row * p.lda),
                (__attribute__((address_space(3))) void*)(&Ahi[sb][w * 512]), 16, 0, 0);
            __builtin_amdgcn_global_load_lds(
                (const __attribute__((address_space(1))) void*)(Ab + (long long)r1row * p.lda),
                (__attribute__((address_space(3))) void*)(&Ahi[sb][2048 + w * 512]), 16, 0, 0);
            if constexpr (AMODE == 3) {
                const ushortT* Ab2 = p.A2 + (long long)bz * p.aBatch
                                   + (long long)bm * 128 * p.lda + k0 + rc;
                __builtin_amdgcn_global_load_lds(
                    (const __attribute__((address_space(1))) void*)(Ab2 + (long long)r0row * p.lda),
                    (__attribute__((address_space(3))) void*)(&Alo[sb][w * 512]), 16, 0, 0);
                __builtin_amdgcn_global_load_lds(
                    (const __attribute__((address_space(1))) void*)(Ab2 + (long long)r1row * p.lda),
                    (__attribute__((address_space(3))) void*)(&Alo[sb][2048 + w * 512]), 16, 0, 0);
            }
        } else {
            const int arow = tid >> 1;
            const float* ap = p.Af + (long long)bz * p.aBatch
                            + ((long long)bm * 128 + arow) * p.lda
                            + k0 + (tid & 1) * 16;
            #pragma unroll
            for (int cc = 0; cc < 2; ++cc) {
                const int c = (tid & 1) * 2 + cc;
                const int cs = (c ^ ((arow >> 1) & 3)) * 8;   // swizzled dest chunk
                float4 v0 = ((const float4*)ap)[cc * 2];
                float4 v1 = ((const float4*)ap)[cc * 2 + 1];
                float vv[8] = {v0.x, v0.y, v0.z, v0.w, v1.x, v1.y, v1.z, v1.w};
                us8 h, l;
                #pragma unroll
                for (int j = 0; j < 8; ++j) {
                    h[j] = (ushortT)(__float_as_uint(vv[j]) >> 16);   // trunc hi
                    l[j] = f2b(vv[j] - b2f(h[j]));                    // exact-ish lo
                }
                *(us8*)(&Ahi[sb][arow * 32 + cs]) = h;
                *(us8*)(&Alo[sb][arow * 32 + cs]) = l;
            }
        }
        {
            const ushortT* Bb = p.B + (long long)bz * p.bBatch
                              + (long long)bn * 128 * p.ldb + k0 + rc;
            __builtin_amdgcn_global_load_lds(
                (const __attribute__((address_space(1))) void*)(Bb + (long long)r0row * p.ldb),
                (__attribute__((address_space(3))) void*)(&Bhi[sb][w * 512]), 16, 0, 0);
            __builtin_amdgcn_global_load_lds(
                (const __attribute__((address_space(1))) void*)(Bb + (long long)r1row * p.ldb),
                (__attribute__((address_space(3))) void*)(&Bhi[sb][2048 + w * 512]), 16, 0, 0);
            if constexpr (BMODE == 1) {
                const ushortT* Bb2 = p.B2 + (long long)bz * p.bBatch
                                   + (long long)bn * 128 * p.ldb + k0 + rc;
                __builtin_amdgcn_global_load_lds(
                    (const __attribute__((address_space(1))) void*)(Bb2 + (long long)r0row * p.ldb),
                    (__attribute__((address_space(3))) void*)(&Blo[sb][w * 512]), 16, 0, 0);
                __builtin_amdgcn_global_load_lds(
                    (const __attribute__((address_space(1))) void*)(Bb2 + (long long)r1row * p.ldb),
                    (__attribute__((address_space(3))) void*)(&Blo[sb][2048 + w * 512]), 16, 0, 0);
            }
        }
    };

    STAGE(0, 0);          // prologue: tile 0 in flight
    int cur = 0;
    for (int t = 0; t < nt; ++t) {
        if (t + 1 < nt) {
            STAGE(cur ^ 1, (t + 1) << 5);   // issue next tile (stays in flight)
            if constexpr (AMODE == 2)
                asm volatile("s_waitcnt lgkmcnt(0)" ::: "memory");
            if constexpr (NLOADS == 8)
                asm volatile("s_waitcnt vmcnt(8)" ::: "memory");
            else
                asm volatile("s_waitcnt vmcnt(4)" ::: "memory");
        } else {
            if constexpr (AMODE == 2)
                asm volatile("s_waitcnt lgkmcnt(0)" ::: "memory");
            asm volatile("s_waitcnt vmcnt(0)" ::: "memory");
        }
        __builtin_amdgcn_s_barrier();          // all slices of cur visible
        __builtin_amdgcn_sched_barrier(0);     // pin ds_reads below the wait
        {
            bf16x8 ah[4], bh[4];
            #pragma unroll
            for (int i = 0; i < 4; ++i)
                ah[i] = *(const bf16x8*)(&Ahi[cur][(wm * 64 + i * 16 + (L & 15)) * 32 + qsw]);
            #pragma unroll
            for (int j = 0; j < 4; ++j)
                bh[j] = *(const bf16x8*)(&Bhi[cur][(wn * 64 + j * 16 + (L & 15)) * 32 + qsw]);
            #pragma unroll
            for (int i = 0; i < 4; ++i)
                #pragma unroll
                for (int j = 0; j < 4; ++j)
                    acc[i][j] = __builtin_amdgcn_mfma_f32_16x16x32_bf16(ah[i], bh[j], acc[i][j], 0, 0, 0);
            if constexpr (BMODE == 1) {
                bf16x8 bl[4];
                #pragma unroll
                for (int j = 0; j < 4; ++j)
                    bl[j] = *(const bf16x8*)(&Blo[cur][(wn * 64 + j * 16 + (L & 15)) * 32 + qsw]);
                #pragma unroll
                for (int i = 0; i < 4; ++i)
                    #pragma unroll
                    for (int j = 0; j < 4; ++j)
                        acc[i][j] = __builtin_amdgcn_mfma_f32_16x16x32_bf16(ah[i], bl[j], acc[i][j], 0, 0, 0);
            }
            if constexpr (AMODE >= 2) {
                bf16x8 al[4];
                #pragma unroll
                for (int i = 0; i < 4; ++i)
                    al[i] = *(const bf16x8*)(&Alo[cur][(wm * 64 + i * 16 + (L & 15)) * 32 + qsw]);
                #pragma unroll
                for (int i = 0; i < 4; ++i)
                    #pragma unroll
                    for (int j = 0; j < 4; ++j)
                        acc[i][j] = __builtin_amdgcn_mfma_f32_16x16x32_bf16(al[i], bh[j], acc[i][j], 0, 0, 0);
            }
        }
        __builtin_amdgcn_sched_barrier(0);     // keep reads above the barrier
        asm volatile("s_waitcnt lgkmcnt(0)" ::: "memory");  // reads complete
        __builtin_amdgcn_s_barrier();          // WAR: before next STAGE overwrite
        cur ^= 1;
    }

    float c0[4], c1[4], c2[4];
    #pragma unroll
    for (int j = 0; j < 4; ++j) {
        if constexpr (EPI == 2) {
            c0[j] = p.pu[bz * SEQ + gnv[j]];
            c1[j] = p.pw[bz * SEQ + gnv[j]];
            c2[j] = p.pz[bz * SEQ + gnv[j]];
        } else if constexpr (EPI == 6) {
            c0[j] = (gnv[j] < p.nSplit) ? p.biasN[gnv[j]]
                                        : p.biasN2[gnv[j] - p.nSplit];
        } else if constexpr (EPI == 4 || EPI == 5 || EPI == 9) {
            c0[j] = p.biasN[gnv[j]];
        }
    }

    #pragma unroll
    for (int i = 0; i < 4; ++i) {
        #pragma unroll
        for (int r = 0; r < 4; ++r) {
            const int gm = bm * 128 + wm * 64 + i * 16 + ((L >> 4) << 2) + r;
            float rA = 0.f, rB = 0.f, mult = 1.f;
            if constexpr (EPI == 2) { rA = p.pe0[bz * SEQ + gm]; rB = p.pe1[bz * SEQ + gm]; }
            if constexpr (EPI == 3) mult = 1.0f / p.pl[bz * SEQ + gm];
            if constexpr (EPI == 8) rA = p.biasM[gm];
            #pragma unroll
            for (int j = 0; j < 4; ++j) {
                float v = acc[i][j][r];
                const long long oidx = obase + (long long)gm * p.ldo + gnv[j];
                if constexpr (EPI == 2) {
                    float s = v * p.scale + rA * c0[j] + rB * c1[j] + c2[j];
                    Of[oidx] = (gnv[j] <= gm) ? __expf(s) : 0.f;
                } else if constexpr (EPI == 3) {
                    float val = v * mult;
                    ushortT h = f2b(val);
                    Oh[oidx] = h; Ol[oidx] = f2b(val - b2f(h));
                } else if constexpr (EPI == 4) {
                    Of[oidx] = v + c0[j] + p.resF32[(long long)gm * p.ldo + gnv[j]];
                } else if constexpr (EPI == 5) {
                    float tt = v + c0[j];
                    Oh[oidx] = f2b(0.5f * tt * (1.0f + erff(tt * 0.70710678118654752f)));
                } else if constexpr (EPI == 6) {
                    float val = v + c0[j];
                    ushortT h = f2b(val);
                    Oh[oidx] = h; Ol[oidx] = f2b(val - b2f(h));
                } else if constexpr (EPI == 8) {
                    float val = v + rA;
                    ushortT h = f2b(val);
                    Oh[oidx] = h; Ol[oidx] = f2b(val - b2f(h));
                } else if constexpr (EPI == 9) {
                    Of[oidx] = v + c0[j];
                }
            }
        }
    }
}

// ------------------------------- host driver --------------------------------
extern "C" void kernel_launch(void* const* d_in, const int* in_sizes, int n_in,
                              void* d_out, int out_size, void* d_ws, size_t ws_size,
                              hipStream_t stream) {
    (void)in_sizes; (void)n_in; (void)out_size; (void)ws_size;
    const float* x    = (const float*)d_in[0];
    const float* wq   = (const float*)d_in[2];
    const float* bq   = (const float*)d_in[3];
    const float* wk   = (const float*)d_in[4];
    const float* bk   = (const float*)d_in[5];
    const float* wv   = (const float*)d_in[6];
    const float* bv   = (const float*)d_in[7];
    const float* wo   = (const float*)d_in[8];
    const float* bo   = (const float*)d_in[9];
    const float* ln1g = (const float*)d_in[10];
    const float* ln1b = (const float*)d_in[11];
    const float* ln2g = (const float*)d_in[12];
    const float* ln2b = (const float*)d_in[13];
    const float* fc1w = (const float*)d_in[14];
    const float* fc1b = (const float*)d_in[15];
    const float* fc2w = (const float*)d_in[16];
    const float* fc2b = (const float*)d_in[17];
    const float* rww  = (const float*)d_in[18];
    const float* rwb  = (const float*)d_in[19];
    const float* cw   = (const float*)d_in[20];
    const float* cb   = (const float*)d_in[21];
    const float* ew   = (const float*)d_in[22];
    const float* eb   = (const float*)d_in[23];
    const float* st   = (const float*)d_in[24];

    char* ws = (char*)d_ws;
    const size_t MB32 = 33554432;
    // s0 h1hi, s1 h1lo | s2+s3 qkhi[16384][2048], s4+s5 qklo | s6 vthi, s7 vtlo
    // wqk bf16 JIT at s6 (8MB, dead before vt GEMM writes s6).
    // After scores: ctxhi->s2, ctxlo->s3 | x1 f32 -> s0+s1 | h2 -> s4,s5
    // FFN: fw -> s6 (32MB) | logc f32 -> s2+s3 (64MB) | ffc bf16 -> s7 (32MB)
    ushortT* h1hi = (ushortT*)(ws + 0 * MB32);
    ushortT* h1lo = (ushortT*)(ws + 1 * MB32);
    ushortT* qkhi = (ushortT*)(ws + 2 * MB32);
    ushortT* qklo = (ushortT*)(ws + 4 * MB32);
    ushortT* vthi = (ushortT*)(ws + 6 * MB32);
    ushortT* vtlo = (ushortT*)(ws + 7 * MB32);
    ushortT* wqkh = (ushortT*)(ws + 6 * MB32);           // 4MB (before vt)
    ushortT* wqkl = wqkh + 2 * (size_t)(HDIM * HDIM);    // 4MB
    ushortT* ctxhi = (ushortT*)(ws + 2 * MB32);
    ushortT* ctxlo = (ushortT*)(ws + 3 * MB32);
    float*   x1   = (float*)(ws + 0 * MB32);
    ushortT* h2hi = (ushortT*)(ws + 4 * MB32);
    ushortT* h2lo = (ushortT*)(ws + 5 * MB32);
    ushortT* fw   = vthi;
    float*   logc = (float*)(ws + 2 * MB32);
    ushortT* ffc  = (ushortT*)(ws + 7 * MB32);
    char* tail = ws + 8 * MB32;
    ushortT* whi = (ushortT*)(tail);                    // 2MB JIT weight hi
    ushortT* wlo = (ushortT*)(tail + 2097152);          // 2MB JIT weight lo
    char* sm = tail + 4194304;
    float* e0v = (float*)(sm);
    float* e1v = (float*)(sm + 1 * 65536);
    float* uu  = (float*)(sm + 2 * 65536);
    float* wwp = (float*)(sm + 3 * 65536);
    float* zz  = (float*)(sm + 4 * 65536);
    float* lrow = (float*)(sm + 5 * 65536);

    const int NW = HDIM * HDIM;
    const int NF = DFF * HDIM;
    ushortT* fc1h = fw;
    ushortT* fc2h = fw + 1 * (size_t)NF;
    ushortT* rwh  = fw + 2 * (size_t)NF;
    ushortT* rwl  = fw + 3 * (size_t)NF;

    float* outx = (float*)d_out;
    float* attn = outx + (size_t)TOK * HDIM;    // f32 [B,1,S,S]

    // --- attention sub-block ---
    ln_k<<<TOK, 256, 0, stream>>>(x, h1hi, h1lo, ln1g, ln1b);

    // qk = h1*[wq;wk]^T + [bq;bk] -> hi+lo  (N=2048 merged)
    cvt2_k<1><<<NW / 1024, 256, 0, stream>>>(wq, wqkh, wqkl);
    cvt2_k<1><<<NW / 1024, 256, 0, stream>>>(wk, wqkh + NW, wqkl + NW);
    GemmP pq{};
    pq.A = h1hi; pq.A2 = h1lo; pq.B = wqkh; pq.B2 = wqkl;
    pq.lda = HDIM; pq.ldb = HDIM; pq.K = HDIM; pq.ldo = 2048;
    pq.out = qkhi; pq.out2 = qklo;
    pq.biasN = bq; pq.biasN2 = bk; pq.nSplit = 1024;
    gemm_nt<6, 3, 1><<<dim3(16, 128, 1), 256, 0, stream>>>(pq);

    // vt[d,t] = wv[d,:]*h1[t,:] + bv[d]  -> hi+lo
    cvt2_k<1><<<NW / 1024, 256, 0, stream>>>(wv, whi, wlo);
    GemmP pv{};
    pv.A = whi; pv.A2 = wlo; pv.B = h1hi; pv.B2 = h1lo;
    pv.lda = HDIM; pv.ldb = HDIM; pv.K = HDIM; pv.ldo = SEQ;
    pv.aBatch = 0; pv.bBatch = (long long)SEQ * HDIM; pv.oBatch = (long long)HDIM * SEQ;
    pv.out = vthi; pv.out2 = vtlo; pv.biasM = bv;
    gemm_nt<8, 3, 1><<<dim3(32, 8, 4), 256, 0, stream>>>(pv);

    bias_pre<<<4096, 256, 0, stream>>>(h1hi, h1lo, cw, cb, ew, eb, st, e0v, e1v, uu, wwp, zz);

    // scores -> exp (q x k from merged buffer; lower triangle only)
    GemmP ps{};
    ps.A = qkhi; ps.A2 = qklo; ps.B = qkhi + 1024; ps.B2 = qklo + 1024;
    ps.lda = 2048; ps.ldb = 2048; ps.K = HDIM; ps.ldo = SEQ;
    ps.aBatch = (long long)SEQ * 2048; ps.bBatch = (long long)SEQ * 2048;
    ps.oBatch = (long long)SEQ * SEQ;
    ps.out = attn; ps.scale = 0.03125f;  // 1/sqrt(1024)
    ps.pe0 = e0v; ps.pe1 = e1v; ps.pu = uu; ps.pw = wwp; ps.pz = zz;
    gemm_nt<2, 3, 1><<<dim3(32, 32, 4), 256, 0, stream>>>(ps);

    row_sum<<<TOK, 256, 0, stream>>>(attn, lrow);

    // ctx = (e * vt^T) / l -> hi+lo   (e f32 staged, vt hi+lo gload_lds)
    GemmP pp{};
    pp.Af = attn; pp.B = vthi; pp.B2 = vtlo;
    pp.lda = SEQ; pp.ldb = SEQ; pp.K = SEQ; pp.ldo = HDIM;
    pp.aBatch = (long long)SEQ * SEQ; pp.bBatch = (long long)HDIM * SEQ;
    pp.oBatch = (long long)SEQ * HDIM;
    pp.out = ctxhi; pp.out2 = ctxlo; pp.pl = lrow;
    gemm_nt<3, 2, 1><<<dim3(8, 32, 4), 256, 0, stream>>>(pp);

    attn_norm<<<32768, 256, 0, stream>>>(attn, lrow);

    // x1 = x + ctx*wo^T + bo  (ctx hi+lo x wo hi+lo JIT)
    cvt2_k<1><<<NW / 1024, 256, 0, stream>>>(wo, whi, wlo);
    GemmP po{};
    po.A = ctxhi; po.A2 = ctxlo; po.B = whi; po.B2 = wlo;
    po.lda = HDIM; po.ldb = HDIM; po.K = HDIM; po.ldo = HDIM;
    po.out = x1; po.biasN = bo; po.resF32 = x;
    gemm_nt<4, 3, 1><<<dim3(8, 128, 1), 256, 0, stream>>>(po);

    // --- sparse FFN sub-block ---
    ln_k<<<TOK, 256, 0, stream>>>(x1, h2hi, h2lo, ln2g, ln2b);

    cvt2_k<0><<<NF / 1024, 256, 0, stream>>>(fc1w, fc1h, nullptr);
    cvt2_k<0><<<NF / 1024, 256, 0, stream>>>(fc2w, fc2h, nullptr);
    cvt2_k<1><<<NF / 1024, 256, 0, stream>>>(rww, rwh, rwl);

    for (int c = 0; c < 4; ++c) {
        const size_t roff = (size_t)c * 4096 * HDIM;
        GemmP pf{};
        pf.A = h2hi + roff; pf.B = fc1h;
        pf.lda = HDIM; pf.ldb = HDIM; pf.K = HDIM; pf.ldo = DFF;
        pf.out = ffc; pf.biasN = fc1b;
        gemm_nt<5, 0, 0><<<dim3(32, 32, 1), 256, 0, stream>>>(pf);

        GemmP pr{};
        pr.A = h2hi + roff; pr.A2 = h2lo + roff; pr.B = rwh; pr.B2 = rwl;
        pr.lda = HDIM; pr.ldb = HDIM; pr.K = HDIM; pr.ldo = DFF;
        pr.out = logc; pr.biasN = rwb;
        gemm_nt<9, 3, 1><<<dim3(32, 32, 1), 256, 0, stream>>>(pr);

        topk_mask<<<4096, 256, 0, stream>>>(logc, ffc);

        GemmP p2{};
        p2.A = ffc; p2.B = fc2h; p2.lda = DFF; p2.ldb = DFF; p2.K = DFF; p2.ldo = HDIM;
        p2.out = outx + roff; p2.biasN = fc2b;
        p2.resF32 = x1 + roff;
        gemm_nt<4, 0, 0><<<dim3(8, 32, 1), 256, 0, stream>>>(p2);
    }
}